// Round 15
// baseline (156.379 us; speedup 1.0000x reference)
//
#include <hip/hip_runtime.h>
#include <hip/hip_bf16.h>

#define NB 16
#define NQ 128
#define NK 512
#define DIN 256   // QS == KS == 256
#define NH 128
#define NDV 256

#define CSC 2.8853900817779268f   // 2*log2(e): tanh(x) = 1 - 2/(1 + 2^(CSC*x))

// Merged projection. Blocks 0..255: Q-proj (8 q-rows each) -> QP[b][q][h]*CSC.
// Blocks 256..1279: K-proj (8 k-rows each) -> KPT[b][h][k]*CSC (transposed via
// LDS tile). W read directly from global as float2 (coalesced 512B/wave,
// L1/L2-resident 64KB) - no W staging, no staging barriers (R14's 32KB W-LDS
// + 8 barriers was a net loss). X tile in 8KB LDS, b128 broadcast reads.
// Thread: h2 = tid&63 -> h {2h2, 2h2+1}; rg = tid>>6 -> rows {rg*2, rg*2+1}.
__global__ __launch_bounds__(256) void proj_both_kernel(
    const float* __restrict__ Q, const float* __restrict__ K,
    const float* __restrict__ Wq, const float* __restrict__ Wk,
    float* __restrict__ QP, float* __restrict__ KPT)
{
    __shared__ float Xl[8 * DIN];   // 8KB; reused as transpose tile (K path)
    const int tid = threadIdx.x;
    int blk = blockIdx.x;
    const float* X; const float2* W2;
    int b, r0, isq;
    if (blk < 256) { isq = 1; b = blk >> 4; r0 = (blk & 15) * 8;
                     X = Q + ((size_t)b * NQ + r0) * DIN; W2 = (const float2*)Wq; }
    else { blk -= 256; isq = 0; b = blk >> 6; r0 = (blk & 63) * 8;
           X = K + ((size_t)b * NK + r0) * DIN; W2 = (const float2*)Wk; }

    {   // stage 8 rows of X: 512 float4, coalesced
        const float4* Xg = (const float4*)X;
        float4* Xs = (float4*)Xl;
        Xs[tid] = Xg[tid];
        Xs[tid + 256] = Xg[tid + 256];
    }
    __syncthreads();

    const int h2 = tid & 63;
    const int rg = tid >> 6;
    float acc[2][2] = {{0.f, 0.f}, {0.f, 0.f}};

    #pragma unroll 8
    for (int d = 0; d < DIN; d += 4) {
        float2 w0 = W2[(d + 0) * 64 + h2];   // coalesced 512B/wave, L1-hit
        float2 w1 = W2[(d + 1) * 64 + h2];
        float2 w2 = W2[(d + 2) * 64 + h2];
        float2 w3 = W2[(d + 3) * 64 + h2];
        #pragma unroll
        for (int r = 0; r < 2; ++r) {
            float4 x = *(const float4*)&Xl[(rg * 2 + r) * DIN + d];  // broadcast
            acc[r][0] += x.x * w0.x + x.y * w1.x + x.z * w2.x + x.w * w3.x;
            acc[r][1] += x.x * w0.y + x.y * w1.y + x.z * w2.y + x.w * w3.y;
        }
    }

    if (isq) {
        #pragma unroll
        for (int r = 0; r < 2; ++r) {
            float2 o; o.x = acc[r][0] * CSC; o.y = acc[r][1] * CSC;
            *(float2*)&QP[((size_t)b * NQ + r0 + rg * 2 + r) * NH + 2 * h2] = o;  // coalesced b64
        }
    } else {
        // transpose via LDS tile T[128 h][12] (pad 12 keeps b128 alignment)
        float* T = Xl;
        __syncthreads();
        #pragma unroll
        for (int r = 0; r < 2; ++r) {
            T[(2 * h2 + 0) * 12 + rg * 2 + r] = acc[r][0] * CSC;
            T[(2 * h2 + 1) * 12 + rg * 2 + r] = acc[r][1] * CSC;
        }
        __syncthreads();
        const int h = tid >> 1, half = tid & 1;
        float4 o = *(const float4*)&T[h * 12 + half * 4];
        *(float4*)&KPT[((size_t)b * NH + h) * NK + r0 + half * 4] = o;
    }
}

// Fused scores + masked softmax + attn@V.  Block = (b, 4 q rows), 512 thr =
// 8 waves, grid 512 -> 4096 waves (16/CU, 2x R14's occupancy).
// Scores: thread owns k=tid x 4 rows (4 indep acc); KPT coalesced; no LDS
// staging, no barriers in hot loop. Softmax: waves 0-3 (one row each).
// Out: wave w covers k in [w*64,(w+1)*64) for all 4 rows (V[b] read once per
// block), 32KB LDS partials, 256-thr reduce.
__global__ __launch_bounds__(512) void attn_fused_kernel(
    const float* __restrict__ QP, const float* __restrict__ KPT,
    const float* __restrict__ wv, const int* __restrict__ vlen,
    const float* __restrict__ V, float* __restrict__ OUT)
{
    __shared__ float qcl[4 * NH];        // 2KB   CSC-scaled q-proj
    __shared__ float wvl[NH];            // 0.5KB -2*wv
    __shared__ float sc[4][NK];          // 8KB   scores -> attn
    __shared__ float part[8][4][NDV];    // 32KB  [wave][row][d] partials
    const int tid = threadIdx.x;
    const int b  = blockIdx.x >> 5;
    const int q0 = (blockIdx.x & 31) * 4;

    qcl[tid] = QP[((size_t)b * NQ + q0) * NH + tid];   // 512 floats, 1 each
    if (tid < NH) wvl[tid] = -2.0f * wv[tid];
    __syncthreads();

    int vl = vlen[b];
    vl = vl < 1 ? 1 : (vl > NK ? NK : vl);

    // ---- scores: score'(r,k) = sum_h wvl[h]/(1 + 2^(qcl[r][h]+kpt[h][k]))
    // (true score minus sum(wv): softmax-invariant row shift)
    {
        const float* kb = KPT + (size_t)b * NH * NK + tid;
        float a0 = 0.f, a1 = 0.f, a2 = 0.f, a3 = 0.f;
        #pragma unroll 4
        for (int h = 0; h < NH; ++h) {
            float kv = kb[(size_t)h * NK];   // coalesced 256B/wave
            float wq = wvl[h];               // broadcast
            float e0 = __builtin_amdgcn_exp2f(qcl[0 * NH + h] + kv);
            float e1 = __builtin_amdgcn_exp2f(qcl[1 * NH + h] + kv);
            float e2 = __builtin_amdgcn_exp2f(qcl[2 * NH + h] + kv);
            float e3 = __builtin_amdgcn_exp2f(qcl[3 * NH + h] + kv);
            a0 += wq * __builtin_amdgcn_rcpf(e0 + 1.0f);
            a1 += wq * __builtin_amdgcn_rcpf(e1 + 1.0f);
            a2 += wq * __builtin_amdgcn_rcpf(e2 + 1.0f);
            a3 += wq * __builtin_amdgcn_rcpf(e3 + 1.0f);
        }
        const bool vld = (tid < vl);
        sc[0][tid] = vld ? a0 : -1e6f;
        sc[1][tid] = vld ? a1 : -1e6f;
        sc[2][tid] = vld ? a2 : -1e6f;
        sc[3][tid] = vld ? a3 : -1e6f;
    }
    __syncthreads();

    // ---- masked softmax: wave w (0..3) owns row w; waves 4-7 wait
    const int w = tid >> 6, lane = tid & 63;
    if (w < 4) {
        float vals[8];
        float m = -3.0e38f;
        #pragma unroll
        for (int i = 0; i < 8; ++i) { vals[i] = sc[w][lane + 64 * i]; m = fmaxf(m, vals[i]); }
        #pragma unroll
        for (int off = 32; off; off >>= 1) m = fmaxf(m, __shfl_xor(m, off, 64));
        float s = 0.f;
        #pragma unroll
        for (int i = 0; i < 8; ++i) {
            vals[i] = __builtin_amdgcn_exp2f((vals[i] - m) * 1.4426950408889634f);
            s += vals[i];
        }
        #pragma unroll
        for (int off = 32; off; off >>= 1) s += __shfl_xor(s, off, 64);
        const float invs = 1.0f / s;   // s >= 1
        #pragma unroll
        for (int i = 0; i < 8; ++i) sc[w][lane + 64 * i] = vals[i] * invs;
    }
    __syncthreads();

    // ---- out partials: wave w handles k in [w*64, w*64+64) for all 4 rows
    {
        float4 o0 = {0,0,0,0}, o1 = {0,0,0,0}, o2 = {0,0,0,0}, o3 = {0,0,0,0};
        const float* vb = V + (size_t)b * NK * NDV + lane * 4;
        const int kb0 = w * 64;
        #pragma unroll 4
        for (int kk = 0; kk < 64; ++kk) {
            const int k = kb0 + kk;
            float4 v4 = *(const float4*)(vb + (size_t)k * NDV);   // 1KB/wave coalesced
            float p0 = sc[0][k], p1 = sc[1][k], p2 = sc[2][k], p3 = sc[3][k];
            o0.x += p0 * v4.x; o0.y += p0 * v4.y; o0.z += p0 * v4.z; o0.w += p0 * v4.w;
            o1.x += p1 * v4.x; o1.y += p1 * v4.y; o1.z += p1 * v4.z; o1.w += p1 * v4.w;
            o2.x += p2 * v4.x; o2.y += p2 * v4.y; o2.z += p2 * v4.z; o2.w += p2 * v4.w;
            o3.x += p3 * v4.x; o3.y += p3 * v4.y; o3.z += p3 * v4.z; o3.w += p3 * v4.w;
        }
        *(float4*)&part[w][0][lane * 4] = o0;
        *(float4*)&part[w][1][lane * 4] = o1;
        *(float4*)&part[w][2][lane * 4] = o2;
        *(float4*)&part[w][3][lane * 4] = o3;
    }
    __syncthreads();

    // ---- reduce 8 partials, store coalesced
    if (tid < 256) {
        const int r = tid >> 6, d4 = tid & 63;
        float4 s = {0, 0, 0, 0};
        #pragma unroll
        for (int p = 0; p < 8; ++p) {
            float4 q = *(const float4*)&part[p][r][d4 * 4];
            s.x += q.x; s.y += q.y; s.z += q.z; s.w += q.w;
        }
        *(float4*)&OUT[((size_t)b * NQ + q0 + r) * NDV + d4 * 4] = s;
    }
}

extern "C" void kernel_launch(void* const* d_in, const int* in_sizes, int n_in,
                              void* d_out, int out_size, void* d_ws, size_t ws_size,
                              hipStream_t stream) {
    const float* queries = (const float*)d_in[0];  // [16,128,256] f32
    const float* keys    = (const float*)d_in[1];  // [16,512,256] f32
    const float* values  = (const float*)d_in[2];  // [16,512,256] f32
    const int*   vlen    = (const int*)d_in[3];    // [16] int32
    const float* Wq      = (const float*)d_in[4];  // [256,128] f32
    const float* Wk      = (const float*)d_in[5];  // [256,128] f32
    const float* wv      = (const float*)d_in[6];  // [128] f32
    float* out           = (float*)d_out;          // [16,128,256] f32

    float* qp  = (float*)d_ws;                     // QP  [16][128][128] = 1MB (CSC-scaled)
    float* kpt = qp + (size_t)NB * NQ * NH;        // KPT [16][128][512] = 4MB (CSC-scaled, transposed)

    proj_both_kernel<<<256 + 1024, 256, 0, stream>>>(queries, keys, Wq, Wk, qp, kpt);
    attn_fused_kernel<<<NB * 32, 512, 0, stream>>>(qp, kpt, wv, vlen, values, out);
}